// Round 1
// baseline (274.012 us; speedup 1.0000x reference)
//
#include <hip/hip_runtime.h>
#include <math.h>

#define QN 8192
#define SN 32768
#define EN 131072
#define DN 256
#define HN 8
#define HDN 32
#define GEON 128
#define FFNN 512

typedef __attribute__((ext_vector_type(8))) short bf16x8;
typedef __attribute__((ext_vector_type(8))) unsigned short u16x8;
typedef __attribute__((ext_vector_type(4))) unsigned short u16x4;
typedef __attribute__((ext_vector_type(4))) float f32x4;

__device__ __forceinline__ unsigned short f2b(float f) {
  union { float f; unsigned u; } v; v.f = f;
  unsigned u = v.u;
  u += 0x7fffu + ((u >> 16) & 1u);   // round-to-nearest-even
  return (unsigned short)(u >> 16);
}
__device__ __forceinline__ float b2f(unsigned short h) {
  union { unsigned u; float f; } v; v.u = ((unsigned)h) << 16; return v.f;
}
__device__ __forceinline__ float gelu_f(float x) {
  return 0.5f * x * (1.0f + erff(x * 0.70710678118654752440f));
}

// ---------------- weight prep: fp32 [K,N] -> bf16 [N,K] ----------------
__device__ __forceinline__ void tr_one(long idx, const float* src, unsigned short* dst, int K, int N) {
  int n = (int)(idx / K);
  int k = (int)(idx % K);
  dst[idx] = f2b(src[(size_t)k * N + n]);
}

__global__ __launch_bounds__(256) void prep_weights(
    const float* Wq, const float* Wk, const float* Wv, const float* Wg,
    const float* Wo, const float* Wf1, const float* Wf2,
    unsigned short* WqT, unsigned short* WkvT, unsigned short* WgT,
    unsigned short* WoT, unsigned short* Wf1T, unsigned short* Wf2T) {
  long i = (long)blockIdx.x * 256 + threadIdx.x;
  if (i < 65536)        tr_one(i,          Wq,  WqT,          256, 256);
  else if (i < 131072)  tr_one(i - 65536,  Wk,  WkvT,         256, 256);
  else if (i < 196608)  tr_one(i - 131072, Wv,  WkvT + 65536, 256, 256);
  else if (i < 229376)  tr_one(i - 196608, Wg,  WgT,          128, 256);
  else if (i < 294912)  tr_one(i - 229376, Wo,  WoT,          256, 256);
  else if (i < 425984)  tr_one(i - 294912, Wf1, Wf1T,         256, 512);
  else if (i < 557056)  tr_one(i - 425984, Wf2, Wf2T,         512, 256);
}

// ---------------- segment offsets from sorted q_idx ----------------
__global__ __launch_bounds__(256) void seg_offsets(const int* q_idx, int* offs) {
  int i = blockIdx.x * 256 + threadIdx.x;
  if (i > QN) return;
  int lo = 0, hi = EN;
  while (lo < hi) {
    int mid = (lo + hi) >> 1;
    if (q_idx[mid] < i) lo = mid + 1; else hi = mid;
  }
  offs[i] = lo;
}

// ---------------- per-query geo stats -> raw [Q,12] ----------------
__global__ __launch_bounds__(256) void geo_stats_kernel(
    const float* qpos, const float* spos, const int* offs, const int* s_idx, float* raw) {
  int q = blockIdx.x * 64 + (threadIdx.x >> 2);
  int sub = threadIdx.x & 3;
  int e0 = offs[q], e1 = offs[q + 1];
  float qx = qpos[q * 3 + 0], qy = qpos[q * 3 + 1], qz = qpos[q * 3 + 2];
  float cnt = 0.f, sx = 0.f, sy = 0.f, sz = 0.f, sxx = 0.f, syy = 0.f, szz = 0.f;
  float mnx = 1e30f, mny = 1e30f, mnz = 1e30f, mxx = -1e30f, mxy = -1e30f, mxz = -1e30f;
  for (int e = e0 + sub; e < e1; e += 4) {
    int s = s_idx[e];
    float rx = spos[s * 3 + 0] - qx;
    float ry = spos[s * 3 + 1] - qy;
    float rz = spos[s * 3 + 2] - qz;
    cnt += 1.f;
    sx += rx; sy += ry; sz += rz;
    sxx += rx * rx; syy += ry * ry; szz += rz * rz;
    mnx = fminf(mnx, rx); mny = fminf(mny, ry); mnz = fminf(mnz, rz);
    mxx = fmaxf(mxx, rx); mxy = fmaxf(mxy, ry); mxz = fmaxf(mxz, rz);
  }
#pragma unroll
  for (int msk = 1; msk <= 2; msk <<= 1) {
    cnt += __shfl_xor(cnt, msk);
    sx += __shfl_xor(sx, msk); sy += __shfl_xor(sy, msk); sz += __shfl_xor(sz, msk);
    sxx += __shfl_xor(sxx, msk); syy += __shfl_xor(syy, msk); szz += __shfl_xor(szz, msk);
    mnx = fminf(mnx, __shfl_xor(mnx, msk));
    mny = fminf(mny, __shfl_xor(mny, msk));
    mnz = fminf(mnz, __shfl_xor(mnz, msk));
    mxx = fmaxf(mxx, __shfl_xor(mxx, msk));
    mxy = fmaxf(mxy, __shfl_xor(mxy, msk));
    mxz = fmaxf(mxz, __shfl_xor(mxz, msk));
  }
  if (sub == 0) {
    float c = fmaxf(cnt, 1.f);
    float mx_ = sx / c, my_ = sy / c, mz_ = sz / c;
    float vx = fmaxf(sxx / c - mx_ * mx_, 0.f);
    float vy = fmaxf(syy / c - my_ * my_, 0.f);
    float vz = fmaxf(szz / c - mz_ * mz_, 0.f);
    float* r = raw + (size_t)q * 12;
    r[0] = mx_; r[1] = my_; r[2] = mz_;
    r[3] = sqrtf(vx); r[4] = sqrtf(vy); r[5] = sqrtf(vz);
    r[6] = fminf(fmaxf(mnx, -100.f), 100.f);
    r[7] = fminf(fmaxf(mny, -100.f), 100.f);
    r[8] = fminf(fmaxf(mnz, -100.f), 100.f);
    r[9] = fminf(fmaxf(mxx, -100.f), 100.f);
    r[10] = fminf(fmaxf(mxy, -100.f), 100.f);
    r[11] = fminf(fmaxf(mxz, -100.f), 100.f);
  }
}

// ---------------- geo MLP: raw [Q,12] -> geo bf16 [Q,128], 8 queries/block ----------------
__global__ __launch_bounds__(128) void geo_mlp_kernel(
    const float* raw, const float* Gw1, const float* Gb1,
    const float* Gw2, const float* Gb2, unsigned short* geo_b) {
  int qb = blockIdx.x * 8;
  int j = threadIdx.x;
  __shared__ float rs[8][12];
  __shared__ float h1[8][128];
  if (j < 96) rs[j / 12][j % 12] = raw[(size_t)(qb + j / 12) * 12 + (j % 12)];
  __syncthreads();
  float b1 = Gb1[j];
  float acc[8];
#pragma unroll
  for (int qq = 0; qq < 8; ++qq) acc[qq] = b1;
  for (int i = 0; i < 12; ++i) {
    float w = Gw1[i * GEON + j];
#pragma unroll
    for (int qq = 0; qq < 8; ++qq) acc[qq] += rs[qq][i] * w;
  }
#pragma unroll
  for (int qq = 0; qq < 8; ++qq) h1[qq][j] = gelu_f(acc[qq]);
  __syncthreads();
  float b2 = Gb2[j];
  float acc2[8];
#pragma unroll
  for (int qq = 0; qq < 8; ++qq) acc2[qq] = b2;
  for (int k = 0; k < 128; ++k) {
    float w = Gw2[k * GEON + j];
#pragma unroll
    for (int qq = 0; qq < 8; ++qq) acc2[qq] += h1[qq][k] * w;
  }
#pragma unroll
  for (int qq = 0; qq < 8; ++qq)
    geo_b[(size_t)(qb + qq) * GEON + j] = f2b(gelu_f(acc2[qq]));
}

// ---------------- layernorm fp32 [Q,256] -> bf16, one wave per row ----------------
__global__ __launch_bounds__(256) void ln_kernel(
    const float* x, const float* g, const float* b, unsigned short* out) {
  int row = blockIdx.x * 4 + (threadIdx.x >> 6);
  int lane = threadIdx.x & 63;
  const float* xr = x + (size_t)row * DN;
  float4 v = *(const float4*)(xr + lane * 4);
  float s = v.x + v.y + v.z + v.w;
  float ss = v.x * v.x + v.y * v.y + v.z * v.z + v.w * v.w;
#pragma unroll
  for (int msk = 1; msk <= 32; msk <<= 1) {
    s += __shfl_xor(s, msk);
    ss += __shfl_xor(ss, msk);
  }
  float mean = s * (1.f / 256.f);
  float var = ss * (1.f / 256.f) - mean * mean;
  float rs = 1.0f / sqrtf(var + 1e-5f);
  float4 gg = *(const float4*)(g + lane * 4);
  float4 bb = *(const float4*)(b + lane * 4);
  unsigned short* o = out + (size_t)row * DN + lane * 4;
  o[0] = f2b((v.x - mean) * rs * gg.x + bb.x);
  o[1] = f2b((v.y - mean) * rs * gg.y + bb.y);
  o[2] = f2b((v.z - mean) * rs * gg.z + bb.z);
  o[3] = f2b((v.w - mean) * rs * gg.w + bb.w);
}

// ---------------- bf16 MFMA GEMM, 64x64 tile, 256 threads ----------------
// C[M,N] = A[M,K] @ B[K,N], BT is bf16 [N,K] row-major.
// A is bf16 [M,K] (or fp32 when A_FP32, converted during staging).
template <bool A_FP32, bool HAS_BIAS, bool DO_GELU, bool HAS_RESID, bool STORE_F32>
__global__ __launch_bounds__(256) void gemm64(
    const void* Ap, const unsigned short* BT, int M, int N, int K,
    const float* bias, const float* resid, float* outF, unsigned short* outB) {
  __shared__ unsigned short As[64][32];
  __shared__ unsigned short Bs[64][32];
  int t = threadIdx.x;
  int bm = blockIdx.y * 64, bn = blockIdx.x * 64;
  int w = t >> 6, lane = t & 63;
  int wr = w >> 1, wc = w & 1;
  int quad = lane >> 4, l16 = lane & 15;
  int row = t >> 2, chunk = t & 3;

  f32x4 acc[2][2];
#pragma unroll
  for (int i = 0; i < 2; ++i)
#pragma unroll
    for (int j = 0; j < 2; ++j) acc[i][j] = (f32x4){0.f, 0.f, 0.f, 0.f};

  for (int k0 = 0; k0 < K; k0 += 32) {
    if (A_FP32) {
      const float* Ag = (const float*)Ap + (size_t)(bm + row) * K + k0 + chunk * 8;
      float4 f0 = *(const float4*)Ag;
      float4 f1 = *(const float4*)(Ag + 4);
      u16x8 u;
      u[0] = f2b(f0.x); u[1] = f2b(f0.y); u[2] = f2b(f0.z); u[3] = f2b(f0.w);
      u[4] = f2b(f1.x); u[5] = f2b(f1.y); u[6] = f2b(f1.z); u[7] = f2b(f1.w);
      *reinterpret_cast<u16x8*>(&As[row][chunk * 8]) = u;
    } else {
      const unsigned short* Ag = (const unsigned short*)Ap + (size_t)(bm + row) * K + k0 + chunk * 8;
      *reinterpret_cast<u16x8*>(&As[row][chunk * 8]) = *reinterpret_cast<const u16x8*>(Ag);
    }
    {
      const unsigned short* Bg = BT + (size_t)(bn + row) * K + k0 + chunk * 8;
      *reinterpret_cast<u16x8*>(&Bs[row][chunk * 8]) = *reinterpret_cast<const u16x8*>(Bg);
    }
    __syncthreads();
    bf16x8 a0 = *reinterpret_cast<const bf16x8*>(&As[wr * 32 + l16][quad * 8]);
    bf16x8 a1 = *reinterpret_cast<const bf16x8*>(&As[wr * 32 + 16 + l16][quad * 8]);
    bf16x8 b0 = *reinterpret_cast<const bf16x8*>(&Bs[wc * 32 + l16][quad * 8]);
    bf16x8 b1 = *reinterpret_cast<const bf16x8*>(&Bs[wc * 32 + 16 + l16][quad * 8]);
    acc[0][0] = __builtin_amdgcn_mfma_f32_16x16x32_bf16(a0, b0, acc[0][0], 0, 0, 0);
    acc[0][1] = __builtin_amdgcn_mfma_f32_16x16x32_bf16(a0, b1, acc[0][1], 0, 0, 0);
    acc[1][0] = __builtin_amdgcn_mfma_f32_16x16x32_bf16(a1, b0, acc[1][0], 0, 0, 0);
    acc[1][1] = __builtin_amdgcn_mfma_f32_16x16x32_bf16(a1, b1, acc[1][1], 0, 0, 0);
    __syncthreads();
  }

#pragma unroll
  for (int i = 0; i < 2; ++i)
#pragma unroll
    for (int j = 0; j < 2; ++j) {
      int col = bn + wc * 32 + j * 16 + l16;
      float bv = HAS_BIAS ? bias[col] : 0.f;
#pragma unroll
      for (int r = 0; r < 4; ++r) {
        int rw = bm + wr * 32 + i * 16 + quad * 4 + r;
        float v = acc[i][j][r] + bv;
        if (DO_GELU) v = gelu_f(v);
        if (HAS_RESID) v += resid[(size_t)rw * N + col];
        if (STORE_F32) outF[(size_t)rw * N + col] = v;
        else outB[(size_t)rw * N + col] = f2b(v);
      }
    }
}

// ---------------- edge attention: one wave per query, online softmax ----------------
__global__ __launch_bounds__(256) void attn_edge_kernel(
    const unsigned short* Qb, const float* Gf, const unsigned short* KVb,
    const int* s_idx, const int* offs, const float* log_tau, unsigned short* attn_b) {
  int q = blockIdx.x * 4 + (threadIdx.x >> 6);
  int lane = threadIdx.x & 63;
  int e0 = offs[q], e1 = offs[q + 1];
  float invs = expf(-log_tau[0]) * 0.17677669529663687f;  // 1/(sqrt(32)*tau)
  int d0 = lane * 4;
  u16x4 qu = *(const u16x4*)(Qb + (size_t)q * DN + d0);
  float q0 = b2f(qu[0]) * invs, q1 = b2f(qu[1]) * invs, q2 = b2f(qu[2]) * invs, q3 = b2f(qu[3]) * invs;
  float4 gv = *(const float4*)(Gf + (size_t)q * DN + d0);
  float m = -INFINITY, l = 0.f;
  float a0 = 0.f, a1 = 0.f, a2 = 0.f, a3 = 0.f;
  for (int e = e0; e < e1; ++e) {
    int s = s_idx[e];
    const unsigned short* kr = KVb + (size_t)s * 512 + d0;
    u16x4 ku = *(const u16x4*)kr;
    u16x4 vu = *(const u16x4*)(kr + 256);
    float p = q0 * b2f(ku[0]) + q1 * b2f(ku[1]) + q2 * b2f(ku[2]) + q3 * b2f(ku[3]);
    p += __shfl_xor(p, 1);
    p += __shfl_xor(p, 2);
    p += __shfl_xor(p, 4);   // per-head score now replicated across the 8 lanes of this head
    float mnew = fmaxf(m, p);
    float sc = expf(m - mnew);       // 0 on first edge (m = -inf)
    float we = expf(p - mnew);
    l = l * sc + we;
    a0 = a0 * sc + we * (b2f(vu[0]) + gv.x);
    a1 = a1 * sc + we * (b2f(vu[1]) + gv.y);
    a2 = a2 * sc + we * (b2f(vu[2]) + gv.z);
    a3 = a3 * sc + we * (b2f(vu[3]) + gv.w);
    m = mnew;
  }
  // reference: M = max(0, seg_max); denom = max(sum exp(s-M), 1e-8)
  float M = fmaxf(m, 0.f);
  float em = expf(m - M);            // 0 if no edges
  float denom = fmaxf(l * em, 1e-8f);
  float f = em / denom;
  unsigned short* o = attn_b + (size_t)q * DN + d0;
  o[0] = f2b(a0 * f); o[1] = f2b(a1 * f); o[2] = f2b(a2 * f); o[3] = f2b(a3 * f);
}

extern "C" void kernel_launch(void* const* d_in, const int* in_sizes, int n_in,
                              void* d_out, int out_size, void* d_ws, size_t ws_size,
                              hipStream_t stream) {
  const float* query_tokens  = (const float*)d_in[0];
  const float* query_pos     = (const float*)d_in[1];
  const float* support_feats = (const float*)d_in[2];
  const float* support_pos   = (const float*)d_in[3];
  const float* Wq  = (const float*)d_in[4];
  const float* Wk  = (const float*)d_in[5];
  const float* Wv  = (const float*)d_in[6];
  const float* Wg  = (const float*)d_in[7];
  const float* Wo  = (const float*)d_in[8];
  const float* bo  = (const float*)d_in[9];
  const float* log_tau = (const float*)d_in[10];
  const float* ln1_g = (const float*)d_in[11];
  const float* ln1_b = (const float*)d_in[12];
  const float* ln2_g = (const float*)d_in[13];
  const float* ln2_b = (const float*)d_in[14];
  const float* Wf1 = (const float*)d_in[15];
  const float* bf1 = (const float*)d_in[16];
  const float* Wf2 = (const float*)d_in[17];
  const float* bf2 = (const float*)d_in[18];
  const float* Gw1 = (const float*)d_in[19];
  const float* Gb1 = (const float*)d_in[20];
  const float* Gw2 = (const float*)d_in[21];
  const float* Gb2 = (const float*)d_in[22];
  const int* q_idx = (const int*)d_in[23];
  const int* s_idx = (const int*)d_in[24];
  float* out = (float*)d_out;

  char* ws = (char*)d_ws;
  size_t off = 0;
  auto alloc = [&](size_t bytes) -> void* {
    void* p = ws + off;
    off = (off + bytes + 255) & ~(size_t)255;
    return p;
  };
  unsigned short* WqT  = (unsigned short*)alloc(65536 * 2);
  unsigned short* WkvT = (unsigned short*)alloc(131072 * 2);
  unsigned short* WgT  = (unsigned short*)alloc(32768 * 2);
  unsigned short* WoT  = (unsigned short*)alloc(65536 * 2);
  unsigned short* Wf1T = (unsigned short*)alloc(131072 * 2);
  unsigned short* Wf2T = (unsigned short*)alloc(131072 * 2);
  int* offs            = (int*)alloc((QN + 1) * 4);
  float* raw           = (float*)alloc((size_t)QN * 12 * 4);
  unsigned short* geo_b = (unsigned short*)alloc((size_t)QN * GEON * 2);
  unsigned short* qt_b  = (unsigned short*)alloc((size_t)QN * DN * 2);
  unsigned short* Qb    = (unsigned short*)alloc((size_t)QN * DN * 2);
  float* GfBuf          = (float*)alloc((size_t)QN * DN * 4);
  unsigned short* KVb   = (unsigned short*)alloc((size_t)SN * 512 * 2);
  unsigned short* attn_b = (unsigned short*)alloc((size_t)QN * DN * 2);
  float* x1             = (float*)alloc((size_t)QN * DN * 4);
  unsigned short* z_b   = (unsigned short*)alloc((size_t)QN * DN * 2);
  unsigned short* h_b   = (unsigned short*)alloc((size_t)QN * FFNN * 2);

  // 1. weight prep (bf16 transposed copies)
  prep_weights<<<2176, 256, 0, stream>>>(Wq, Wk, Wv, Wg, Wo, Wf1, Wf2,
                                         WqT, WkvT, WgT, WoT, Wf1T, Wf2T);
  // 2. segment offsets
  seg_offsets<<<33, 256, 0, stream>>>(q_idx, offs);
  // 3. geo stats
  geo_stats_kernel<<<QN / 64, 256, 0, stream>>>(query_pos, support_pos, offs, s_idx, raw);
  // 4. geo MLP
  geo_mlp_kernel<<<QN / 8, 128, 0, stream>>>(raw, Gw1, Gb1, Gw2, Gb2, geo_b);
  // 5. LN1
  ln_kernel<<<QN / 4, 256, 0, stream>>>(query_tokens, ln1_g, ln1_b, qt_b);
  // 6. KV = support_feats @ [Wk|Wv]  (A fp32 -> bf16 in staging), store bf16
  gemm64<true, false, false, false, false><<<dim3(512 / 64, SN / 64), 256, 0, stream>>>(
      support_feats, WkvT, SN, 512, 256, nullptr, nullptr, nullptr, KVb);
  // 7. Qf = qt @ Wq, store bf16
  gemm64<false, false, false, false, false><<<dim3(DN / 64, QN / 64), 256, 0, stream>>>(
      qt_b, WqT, QN, DN, 256, nullptr, nullptr, nullptr, Qb);
  // 8. Gf = geo @ Wg, store fp32
  gemm64<false, false, false, false, true><<<dim3(DN / 64, QN / 64), 256, 0, stream>>>(
      geo_b, WgT, QN, DN, 128, nullptr, nullptr, GfBuf, nullptr);
  // 9. edge attention -> attn_b bf16
  attn_edge_kernel<<<QN / 4, 256, 0, stream>>>(Qb, GfBuf, KVb, s_idx, offs, log_tau, attn_b);
  // 10. x1 = attn @ Wo + bo + query_tokens, store fp32
  gemm64<false, true, false, true, true><<<dim3(DN / 64, QN / 64), 256, 0, stream>>>(
      attn_b, WoT, QN, DN, 256, bo, query_tokens, x1, nullptr);
  // 11. LN2
  ln_kernel<<<QN / 4, 256, 0, stream>>>(x1, ln2_g, ln2_b, z_b);
  // 12. h = gelu(z @ Wf1 + bf1), store bf16
  gemm64<false, true, true, false, false><<<dim3(FFNN / 64, QN / 64), 256, 0, stream>>>(
      z_b, Wf1T, QN, FFNN, 256, bf1, nullptr, nullptr, h_b);
  // 13. out = h @ Wf2 + bf2 + x1, store fp32 -> d_out
  gemm64<false, true, false, true, true><<<dim3(DN / 64, QN / 64), 256, 0, stream>>>(
      h_b, Wf2T, QN, DN, 512, bf2, x1, out, nullptr);

  (void)in_sizes; (void)n_in; (void)out_size; (void)ws_size; (void)d_ws;
}

// Round 5
// 258.714 us; speedup vs baseline: 1.0591x; 1.0591x over previous
//
#include <hip/hip_runtime.h>
#include <math.h>

#define QN 8192
#define SN 32768
#define EN 131072
#define DN 256
#define HN 8
#define HDN 32
#define GEON 128
#define FFNN 512

typedef __attribute__((ext_vector_type(8))) short bf16x8;
typedef __attribute__((ext_vector_type(8))) unsigned short u16x8;
typedef __attribute__((ext_vector_type(4))) unsigned short u16x4;
typedef __attribute__((ext_vector_type(4))) float f32x4;

__device__ __forceinline__ unsigned short f2b(float f) {
  union { float f; unsigned u; } v; v.f = f;
  unsigned u = v.u;
  u += 0x7fffu + ((u >> 16) & 1u);   // round-to-nearest-even
  return (unsigned short)(u >> 16);
}
__device__ __forceinline__ float b2f(unsigned short h) {
  union { unsigned u; float f; } v; v.u = ((unsigned)h) << 16; return v.f;
}
__device__ __forceinline__ float gelu_f(float x) {
  return 0.5f * x * (1.0f + erff(x * 0.70710678118654752440f));
}

// ---------------- weight prep: fp32 [K,N] -> bf16 [N,K] (R1 version) ----------------
__device__ __forceinline__ void tr_one(long idx, const float* src, unsigned short* dst, int K, int N) {
  int n = (int)(idx / K);
  int k = (int)(idx % K);
  dst[idx] = f2b(src[(size_t)k * N + n]);
}

__global__ __launch_bounds__(256) void prep_weights(
    const float* Wq, const float* Wk, const float* Wv, const float* Wg,
    const float* Wo, const float* Wf1, const float* Wf2,
    unsigned short* WqT, unsigned short* WkvT, unsigned short* WgT,
    unsigned short* WoT, unsigned short* Wf1T, unsigned short* Wf2T) {
  long i = (long)blockIdx.x * 256 + threadIdx.x;
  if (i < 65536)        tr_one(i,          Wq,  WqT,          256, 256);
  else if (i < 131072)  tr_one(i - 65536,  Wk,  WkvT,         256, 256);
  else if (i < 196608)  tr_one(i - 131072, Wv,  WkvT + 65536, 256, 256);
  else if (i < 229376)  tr_one(i - 196608, Wg,  WgT,          128, 256);
  else if (i < 294912)  tr_one(i - 229376, Wo,  WoT,          256, 256);
  else if (i < 425984)  tr_one(i - 294912, Wf1, Wf1T,         256, 512);
  else if (i < 557056)  tr_one(i - 425984, Wf2, Wf2T,         512, 256);
}

// ---------------- segment offsets from sorted q_idx ----------------
__global__ __launch_bounds__(256) void seg_offsets(const int* q_idx, int* offs) {
  int i = blockIdx.x * 256 + threadIdx.x;
  if (i > QN) return;
  int lo = 0, hi = EN;
  while (lo < hi) {
    int mid = (lo + hi) >> 1;
    if (q_idx[mid] < i) lo = mid + 1; else hi = mid;
  }
  offs[i] = lo;
}

// ---------------- per-query geo stats -> raw [Q,12] ----------------
__global__ __launch_bounds__(256) void geo_stats_kernel(
    const float* qpos, const float* spos, const int* offs, const int* s_idx, float* raw) {
  int q = blockIdx.x * 64 + (threadIdx.x >> 2);
  int sub = threadIdx.x & 3;
  int e0 = offs[q], e1 = offs[q + 1];
  float qx = qpos[q * 3 + 0], qy = qpos[q * 3 + 1], qz = qpos[q * 3 + 2];
  float cnt = 0.f, sx = 0.f, sy = 0.f, sz = 0.f, sxx = 0.f, syy = 0.f, szz = 0.f;
  float mnx = 1e30f, mny = 1e30f, mnz = 1e30f, mxx = -1e30f, mxy = -1e30f, mxz = -1e30f;
  for (int e = e0 + sub; e < e1; e += 4) {
    int s = s_idx[e];
    float rx = spos[s * 3 + 0] - qx;
    float ry = spos[s * 3 + 1] - qy;
    float rz = spos[s * 3 + 2] - qz;
    cnt += 1.f;
    sx += rx; sy += ry; sz += rz;
    sxx += rx * rx; syy += ry * ry; szz += rz * rz;
    mnx = fminf(mnx, rx); mny = fminf(mny, ry); mnz = fminf(mnz, rz);
    mxx = fmaxf(mxx, rx); mxy = fmaxf(mxy, ry); mxz = fmaxf(mxz, rz);
  }
#pragma unroll
  for (int msk = 1; msk <= 2; msk <<= 1) {
    cnt += __shfl_xor(cnt, msk);
    sx += __shfl_xor(sx, msk); sy += __shfl_xor(sy, msk); sz += __shfl_xor(sz, msk);
    sxx += __shfl_xor(sxx, msk); syy += __shfl_xor(syy, msk); szz += __shfl_xor(szz, msk);
    mnx = fminf(mnx, __shfl_xor(mnx, msk));
    mny = fminf(mny, __shfl_xor(mny, msk));
    mnz = fminf(mnz, __shfl_xor(mnz, msk));
    mxx = fmaxf(mxx, __shfl_xor(mxx, msk));
    mxy = fmaxf(mxy, __shfl_xor(mxy, msk));
    mxz = fmaxf(mxz, __shfl_xor(mxz, msk));
  }
  if (sub == 0) {
    float c = fmaxf(cnt, 1.f);
    float mx_ = sx / c, my_ = sy / c, mz_ = sz / c;
    float vx = fmaxf(sxx / c - mx_ * mx_, 0.f);
    float vy = fmaxf(syy / c - my_ * my_, 0.f);
    float vz = fmaxf(szz / c - mz_ * mz_, 0.f);
    float* r = raw + (size_t)q * 12;
    r[0] = mx_; r[1] = my_; r[2] = mz_;
    r[3] = sqrtf(vx); r[4] = sqrtf(vy); r[5] = sqrtf(vz);
    r[6] = fminf(fmaxf(mnx, -100.f), 100.f);
    r[7] = fminf(fmaxf(mny, -100.f), 100.f);
    r[8] = fminf(fmaxf(mnz, -100.f), 100.f);
    r[9] = fminf(fmaxf(mxx, -100.f), 100.f);
    r[10] = fminf(fmaxf(mxy, -100.f), 100.f);
    r[11] = fminf(fmaxf(mxz, -100.f), 100.f);
  }
}

// ---------------- geo MLP: raw [Q,12] -> geo bf16 [Q,128], 8 queries/block ----------------
__global__ __launch_bounds__(128) void geo_mlp_kernel(
    const float* raw, const float* Gw1, const float* Gb1,
    const float* Gw2, const float* Gb2, unsigned short* geo_b) {
  int qb = blockIdx.x * 8;
  int j = threadIdx.x;
  __shared__ float rs[8][12];
  __shared__ float h1[8][128];
  if (j < 96) rs[j / 12][j % 12] = raw[(size_t)(qb + j / 12) * 12 + (j % 12)];
  __syncthreads();
  float b1 = Gb1[j];
  float acc[8];
#pragma unroll
  for (int qq = 0; qq < 8; ++qq) acc[qq] = b1;
  for (int i = 0; i < 12; ++i) {
    float w = Gw1[i * GEON + j];
#pragma unroll
    for (int qq = 0; qq < 8; ++qq) acc[qq] += rs[qq][i] * w;
  }
#pragma unroll
  for (int qq = 0; qq < 8; ++qq) h1[qq][j] = gelu_f(acc[qq]);
  __syncthreads();
  float b2 = Gb2[j];
  float acc2[8];
#pragma unroll
  for (int qq = 0; qq < 8; ++qq) acc2[qq] = b2;
  for (int k = 0; k < 128; ++k) {
    float w = Gw2[k * GEON + j];
#pragma unroll
    for (int qq = 0; qq < 8; ++qq) acc2[qq] += h1[qq][k] * w;
  }
#pragma unroll
  for (int qq = 0; qq < 8; ++qq)
    geo_b[(size_t)(qb + qq) * GEON + j] = f2b(gelu_f(acc2[qq]));
}

// ---------------- layernorm fp32 [Q,256] -> bf16, one wave per row ----------------
__global__ __launch_bounds__(256) void ln_kernel(
    const float* x, const float* g, const float* b, unsigned short* out) {
  int row = blockIdx.x * 4 + (threadIdx.x >> 6);
  int lane = threadIdx.x & 63;
  const float* xr = x + (size_t)row * DN;
  float4 v = *(const float4*)(xr + lane * 4);
  float s = v.x + v.y + v.z + v.w;
  float ss = v.x * v.x + v.y * v.y + v.z * v.z + v.w * v.w;
#pragma unroll
  for (int msk = 1; msk <= 32; msk <<= 1) {
    s += __shfl_xor(s, msk);
    ss += __shfl_xor(ss, msk);
  }
  float mean = s * (1.f / 256.f);
  float var = ss * (1.f / 256.f) - mean * mean;
  float rs = 1.0f / sqrtf(var + 1e-5f);
  float4 gg = *(const float4*)(g + lane * 4);
  float4 bb = *(const float4*)(b + lane * 4);
  unsigned short* o = out + (size_t)row * DN + lane * 4;
  o[0] = f2b((v.x - mean) * rs * gg.x + bb.x);
  o[1] = f2b((v.y - mean) * rs * gg.y + bb.y);
  o[2] = f2b((v.z - mean) * rs * gg.z + bb.z);
  o[3] = f2b((v.w - mean) * rs * gg.w + bb.w);
}

// ---------------- bf16 MFMA GEMM, 64x64 tile, 256 threads (R1 + pad + COLGRID) ----------------
// C[M,N] = A[M,K] @ B[K,N], BT is bf16 [N,K] row-major.
// A is bf16 [M,K] (or fp32 when A_FP32, converted during staging).
// COLGRID: grid is dim3(Mtiles, Ntiles) so linear block id maps all N-tiles of
// one M-tile to the same XCD (bx%8) -> A-tile fetched ~once per row-tile.
// LDS pad 40 (80 B stride): rows r,r+8 alias -> 2-way only, free per m136.
template <bool A_FP32, bool COLGRID, bool HAS_BIAS, bool DO_GELU, bool HAS_RESID, bool STORE_F32>
__global__ __launch_bounds__(256) void gemm64(
    const void* Ap, const unsigned short* BT, int M, int N, int K,
    const float* bias, const float* resid, float* outF, unsigned short* outB) {
  __shared__ unsigned short As[64][40];
  __shared__ unsigned short Bs[64][40];
  int t = threadIdx.x;
  int bm = (COLGRID ? blockIdx.x : blockIdx.y) * 64;
  int bn = (COLGRID ? blockIdx.y : blockIdx.x) * 64;
  int w = t >> 6, lane = t & 63;
  int wr = w >> 1, wc = w & 1;
  int quad = lane >> 4, l16 = lane & 15;
  int row = t >> 2, chunk = t & 3;

  f32x4 acc[2][2];
#pragma unroll
  for (int i = 0; i < 2; ++i)
#pragma unroll
    for (int j = 0; j < 2; ++j) acc[i][j] = (f32x4){0.f, 0.f, 0.f, 0.f};

  for (int k0 = 0; k0 < K; k0 += 32) {
    if (A_FP32) {
      const float* Ag = (const float*)Ap + (size_t)(bm + row) * K + k0 + chunk * 8;
      float4 f0 = *(const float4*)Ag;
      float4 f1 = *(const float4*)(Ag + 4);
      u16x8 u;
      u[0] = f2b(f0.x); u[1] = f2b(f0.y); u[2] = f2b(f0.z); u[3] = f2b(f0.w);
      u[4] = f2b(f1.x); u[5] = f2b(f1.y); u[6] = f2b(f1.z); u[7] = f2b(f1.w);
      *reinterpret_cast<u16x8*>(&As[row][chunk * 8]) = u;
    } else {
      const unsigned short* Ag = (const unsigned short*)Ap + (size_t)(bm + row) * K + k0 + chunk * 8;
      *reinterpret_cast<u16x8*>(&As[row][chunk * 8]) = *reinterpret_cast<const u16x8*>(Ag);
    }
    {
      const unsigned short* Bg = BT + (size_t)(bn + row) * K + k0 + chunk * 8;
      *reinterpret_cast<u16x8*>(&Bs[row][chunk * 8]) = *reinterpret_cast<const u16x8*>(Bg);
    }
    __syncthreads();
    bf16x8 a0 = *reinterpret_cast<const bf16x8*>(&As[wr * 32 + l16][quad * 8]);
    bf16x8 a1 = *reinterpret_cast<const bf16x8*>(&As[wr * 32 + 16 + l16][quad * 8]);
    bf16x8 b0 = *reinterpret_cast<const bf16x8*>(&Bs[wc * 32 + l16][quad * 8]);
    bf16x8 b1 = *reinterpret_cast<const bf16x8*>(&Bs[wc * 32 + 16 + l16][quad * 8]);
    acc[0][0] = __builtin_amdgcn_mfma_f32_16x16x32_bf16(a0, b0, acc[0][0], 0, 0, 0);
    acc[0][1] = __builtin_amdgcn_mfma_f32_16x16x32_bf16(a0, b1, acc[0][1], 0, 0, 0);
    acc[1][0] = __builtin_amdgcn_mfma_f32_16x16x32_bf16(a1, b0, acc[1][0], 0, 0, 0);
    acc[1][1] = __builtin_amdgcn_mfma_f32_16x16x32_bf16(a1, b1, acc[1][1], 0, 0, 0);
    __syncthreads();
  }

#pragma unroll
  for (int i = 0; i < 2; ++i)
#pragma unroll
    for (int j = 0; j < 2; ++j) {
      int col = bn + wc * 32 + j * 16 + l16;
      float bv = HAS_BIAS ? bias[col] : 0.f;
#pragma unroll
      for (int r = 0; r < 4; ++r) {
        int rw = bm + wr * 32 + i * 16 + quad * 4 + r;
        float v = acc[i][j][r] + bv;
        if (DO_GELU) v = gelu_f(v);
        if (HAS_RESID) v += resid[(size_t)rw * N + col];
        if (STORE_F32) outF[(size_t)rw * N + col] = v;
        else outB[(size_t)rw * N + col] = f2b(v);
      }
    }
}

// ---------------- edge attention: one wave per query, online softmax ----------------
__global__ __launch_bounds__(256) void attn_edge_kernel(
    const unsigned short* Qb, const float* Gf, const unsigned short* KVb,
    const int* s_idx, const int* offs, const float* log_tau, unsigned short* attn_b) {
  int q = blockIdx.x * 4 + (threadIdx.x >> 6);
  int lane = threadIdx.x & 63;
  int e0 = offs[q], e1 = offs[q + 1];
  float invs = expf(-log_tau[0]) * 0.17677669529663687f;  // 1/(sqrt(32)*tau)
  int d0 = lane * 4;
  u16x4 qu = *(const u16x4*)(Qb + (size_t)q * DN + d0);
  float q0 = b2f(qu[0]) * invs, q1 = b2f(qu[1]) * invs, q2 = b2f(qu[2]) * invs, q3 = b2f(qu[3]) * invs;
  float4 gv = *(const float4*)(Gf + (size_t)q * DN + d0);
  float m = -INFINITY, l = 0.f;
  float a0 = 0.f, a1 = 0.f, a2 = 0.f, a3 = 0.f;
  for (int e = e0; e < e1; ++e) {
    int s = s_idx[e];
    const unsigned short* kr = KVb + (size_t)s * 512 + d0;
    u16x4 ku = *(const u16x4*)kr;
    u16x4 vu = *(const u16x4*)(kr + 256);
    float p = q0 * b2f(ku[0]) + q1 * b2f(ku[1]) + q2 * b2f(ku[2]) + q3 * b2f(ku[3]);
    p += __shfl_xor(p, 1);
    p += __shfl_xor(p, 2);
    p += __shfl_xor(p, 4);   // per-head score replicated across the head's 8 lanes
    float mnew = fmaxf(m, p);
    float sc = expf(m - mnew);       // 0 on first edge (m = -inf)
    float we = expf(p - mnew);
    l = l * sc + we;
    a0 = a0 * sc + we * (b2f(vu[0]) + gv.x);
    a1 = a1 * sc + we * (b2f(vu[1]) + gv.y);
    a2 = a2 * sc + we * (b2f(vu[2]) + gv.z);
    a3 = a3 * sc + we * (b2f(vu[3]) + gv.w);
    m = mnew;
  }
  // reference: M = max(0, seg_max); denom = max(sum exp(s-M), 1e-8)
  float M = fmaxf(m, 0.f);
  float em = expf(m - M);            // 0 if no edges
  float denom = fmaxf(l * em, 1e-8f);
  float f = em / denom;
  unsigned short* o = attn_b + (size_t)q * DN + d0;
  o[0] = f2b(a0 * f); o[1] = f2b(a1 * f); o[2] = f2b(a2 * f); o[3] = f2b(a3 * f);
}

extern "C" void kernel_launch(void* const* d_in, const int* in_sizes, int n_in,
                              void* d_out, int out_size, void* d_ws, size_t ws_size,
                              hipStream_t stream) {
  const float* query_tokens  = (const float*)d_in[0];
  const float* query_pos     = (const float*)d_in[1];
  const float* support_feats = (const float*)d_in[2];
  const float* support_pos   = (const float*)d_in[3];
  const float* Wq  = (const float*)d_in[4];
  const float* Wk  = (const float*)d_in[5];
  const float* Wv  = (const float*)d_in[6];
  const float* Wg  = (const float*)d_in[7];
  const float* Wo  = (const float*)d_in[8];
  const float* bo  = (const float*)d_in[9];
  const float* log_tau = (const float*)d_in[10];
  const float* ln1_g = (const float*)d_in[11];
  const float* ln1_b = (const float*)d_in[12];
  const float* ln2_g = (const float*)d_in[13];
  const float* ln2_b = (const float*)d_in[14];
  const float* Wf1 = (const float*)d_in[15];
  const float* bf1 = (const float*)d_in[16];
  const float* Wf2 = (const float*)d_in[17];
  const float* bf2 = (const float*)d_in[18];
  const float* Gw1 = (const float*)d_in[19];
  const float* Gb1 = (const float*)d_in[20];
  const float* Gw2 = (const float*)d_in[21];
  const float* Gb2 = (const float*)d_in[22];
  const int* q_idx = (const int*)d_in[23];
  const int* s_idx = (const int*)d_in[24];
  float* out = (float*)d_out;

  char* ws = (char*)d_ws;
  size_t off = 0;
  auto alloc = [&](size_t bytes) -> void* {
    void* p = ws + off;
    off = (off + bytes + 255) & ~(size_t)255;
    return p;
  };
  unsigned short* WqT  = (unsigned short*)alloc(65536 * 2);
  unsigned short* WkvT = (unsigned short*)alloc(131072 * 2);
  unsigned short* WgT  = (unsigned short*)alloc(32768 * 2);
  unsigned short* WoT  = (unsigned short*)alloc(65536 * 2);
  unsigned short* Wf1T = (unsigned short*)alloc(131072 * 2);
  unsigned short* Wf2T = (unsigned short*)alloc(131072 * 2);
  int* offs            = (int*)alloc((QN + 1) * 4);
  float* raw           = (float*)alloc((size_t)QN * 12 * 4);
  unsigned short* geo_b = (unsigned short*)alloc((size_t)QN * GEON * 2);
  unsigned short* qt_b  = (unsigned short*)alloc((size_t)QN * DN * 2);
  unsigned short* Qb    = (unsigned short*)alloc((size_t)QN * DN * 2);
  float* GfBuf          = (float*)alloc((size_t)QN * DN * 4);
  unsigned short* KVb   = (unsigned short*)alloc((size_t)SN * 512 * 2);
  unsigned short* attn_b = (unsigned short*)alloc((size_t)QN * DN * 2);
  float* x1             = (float*)alloc((size_t)QN * DN * 4);
  unsigned short* z_b   = (unsigned short*)alloc((size_t)QN * DN * 2);
  unsigned short* h_b   = (unsigned short*)alloc((size_t)QN * FFNN * 2);

  // 1. weight prep (bf16 transposed copies)
  prep_weights<<<2176, 256, 0, stream>>>(Wq, Wk, Wv, Wg, Wo, Wf1, Wf2,
                                         WqT, WkvT, WgT, WoT, Wf1T, Wf2T);
  // 2. segment offsets
  seg_offsets<<<33, 256, 0, stream>>>(q_idx, offs);
  // 3. geo stats
  geo_stats_kernel<<<QN / 64, 256, 0, stream>>>(query_pos, support_pos, offs, s_idx, raw);
  // 4. geo MLP
  geo_mlp_kernel<<<QN / 8, 128, 0, stream>>>(raw, Gw1, Gb1, Gw2, Gb2, geo_b);
  // 5. LN1
  ln_kernel<<<QN / 4, 256, 0, stream>>>(query_tokens, ln1_g, ln1_b, qt_b);
  // 6. KV = support_feats @ [Wk|Wv]  (A fp32 -> bf16 in staging), store bf16
  gemm64<true, true, false, false, false, false><<<dim3(SN / 64, 512 / 64), 256, 0, stream>>>(
      support_feats, WkvT, SN, 512, 256, nullptr, nullptr, nullptr, KVb);
  // 7. Qf = qt @ Wq, store bf16
  gemm64<false, true, false, false, false, false><<<dim3(QN / 64, DN / 64), 256, 0, stream>>>(
      qt_b, WqT, QN, DN, 256, nullptr, nullptr, nullptr, Qb);
  // 8. Gf = geo @ Wg, store fp32
  gemm64<false, true, false, false, false, true><<<dim3(QN / 64, DN / 64), 256, 0, stream>>>(
      geo_b, WgT, QN, DN, 128, nullptr, nullptr, GfBuf, nullptr);
  // 9. edge attention -> attn_b bf16
  attn_edge_kernel<<<QN / 4, 256, 0, stream>>>(Qb, GfBuf, KVb, s_idx, offs, log_tau, attn_b);
  // 10. x1 = attn @ Wo + bo + query_tokens, store fp32
  gemm64<false, true, true, false, true, true><<<dim3(QN / 64, DN / 64), 256, 0, stream>>>(
      attn_b, WoT, QN, DN, 256, bo, query_tokens, x1, nullptr);
  // 11. LN2
  ln_kernel<<<QN / 4, 256, 0, stream>>>(x1, ln2_g, ln2_b, z_b);
  // 12. h = gelu(z @ Wf1 + bf1), store bf16
  gemm64<false, true, true, true, false, false><<<dim3(QN / 64, FFNN / 64), 256, 0, stream>>>(
      z_b, Wf1T, QN, FFNN, 256, bf1, nullptr, nullptr, h_b);
  // 13. out = h @ Wf2 + bf2 + x1, store fp32 -> d_out
  gemm64<false, true, true, false, true, true><<<dim3(QN / 64, DN / 64), 256, 0, stream>>>(
      h_b, Wf2T, QN, DN, 512, bf2, x1, out, nullptr);

  (void)in_sizes; (void)n_in; (void)out_size; (void)ws_size;
}

// Round 6
// 250.945 us; speedup vs baseline: 1.0919x; 1.0310x over previous
//
#include <hip/hip_runtime.h>
#include <math.h>

#define QN 8192
#define SN 32768
#define EN 131072
#define DN 256
#define HN 8
#define HDN 32
#define GEON 128
#define FFNN 512

typedef __attribute__((ext_vector_type(8))) short bf16x8;
typedef __attribute__((ext_vector_type(8))) unsigned short u16x8;
typedef __attribute__((ext_vector_type(4))) unsigned short u16x4;
typedef __attribute__((ext_vector_type(4))) float f32x4;

__device__ __forceinline__ unsigned short f2b(float f) {
  union { float f; unsigned u; } v; v.f = f;
  unsigned u = v.u;
  u += 0x7fffu + ((u >> 16) & 1u);   // round-to-nearest-even
  return (unsigned short)(u >> 16);
}
__device__ __forceinline__ float b2f(unsigned short h) {
  union { unsigned u; float f; } v; v.u = ((unsigned)h) << 16; return v.f;
}
__device__ __forceinline__ float gelu_f(float x) {
  return 0.5f * x * (1.0f + erff(x * 0.70710678118654752440f));
}

// ---------------- tiled transpose: fp32 [K,N] -> bf16 [N,K] ----------------
// 64x64 tiles via LDS; coalesced float4 reads, coalesced ushort4 writes.
// ts pad [65]: column reads are exactly 2-way bank aliased (free, m136).
__global__ __launch_bounds__(256) void transpose_weights(
    const float* Wq, const float* Wk, const float* Wv, const float* Wg,
    const float* Wo, const float* Wf1, const float* Wf2,
    unsigned short* WqT, unsigned short* WkvT, unsigned short* WgT,
    unsigned short* WoT, unsigned short* Wf1T, unsigned short* Wf2T) {
  int b = blockIdx.x;
  const float* src; unsigned short* dst; int K, N, tile;
  if (b < 16)       { src = Wq;  dst = WqT;          K = 256; N = 256; tile = b; }
  else if (b < 32)  { src = Wk;  dst = WkvT;         K = 256; N = 256; tile = b - 16; }
  else if (b < 48)  { src = Wv;  dst = WkvT + 65536; K = 256; N = 256; tile = b - 32; }
  else if (b < 56)  { src = Wg;  dst = WgT;          K = 128; N = 256; tile = b - 48; }
  else if (b < 72)  { src = Wo;  dst = WoT;          K = 256; N = 256; tile = b - 56; }
  else if (b < 104) { src = Wf1; dst = Wf1T;         K = 256; N = 512; tile = b - 72; }
  else              { src = Wf2; dst = Wf2T;         K = 512; N = 256; tile = b - 104; }
  int ktiles = K >> 6;
  int k0 = (tile % ktiles) * 64, n0 = (tile / ktiles) * 64;
  __shared__ float ts[64][65];
  int t = threadIdx.x;
  int c4 = (t & 15) * 4;
  int r = t >> 4;
#pragma unroll
  for (int p = 0; p < 4; ++p) {
    int row = p * 16 + r;
    float4 v = *(const float4*)(src + (size_t)(k0 + row) * N + n0 + c4);
    ts[row][c4 + 0] = v.x; ts[row][c4 + 1] = v.y;
    ts[row][c4 + 2] = v.z; ts[row][c4 + 3] = v.w;
  }
  __syncthreads();
#pragma unroll
  for (int p = 0; p < 4; ++p) {
    int n = p * 16 + r;
    ushort4 o;
    o.x = f2b(ts[c4 + 0][n]); o.y = f2b(ts[c4 + 1][n]);
    o.z = f2b(ts[c4 + 2][n]); o.w = f2b(ts[c4 + 3][n]);
    *(ushort4*)(dst + (size_t)(n0 + n) * K + k0 + c4) = o;
  }
}

// ---------------- segment offsets from sorted q_idx ----------------
__global__ __launch_bounds__(256) void seg_offsets(const int* q_idx, int* offs) {
  int i = blockIdx.x * 256 + threadIdx.x;
  if (i > QN) return;
  int lo = 0, hi = EN;
  while (lo < hi) {
    int mid = (lo + hi) >> 1;
    if (q_idx[mid] < i) lo = mid + 1; else hi = mid;
  }
  offs[i] = lo;
}

// ---------------- per-query geo stats -> raw [Q,12] ----------------
__global__ __launch_bounds__(256) void geo_stats_kernel(
    const float* qpos, const float* spos, const int* offs, const int* s_idx, float* raw) {
  int q = blockIdx.x * 64 + (threadIdx.x >> 2);
  int sub = threadIdx.x & 3;
  int e0 = offs[q], e1 = offs[q + 1];
  float qx = qpos[q * 3 + 0], qy = qpos[q * 3 + 1], qz = qpos[q * 3 + 2];
  float cnt = 0.f, sx = 0.f, sy = 0.f, sz = 0.f, sxx = 0.f, syy = 0.f, szz = 0.f;
  float mnx = 1e30f, mny = 1e30f, mnz = 1e30f, mxx = -1e30f, mxy = -1e30f, mxz = -1e30f;
  for (int e = e0 + sub; e < e1; e += 4) {
    int s = s_idx[e];
    float rx = spos[s * 3 + 0] - qx;
    float ry = spos[s * 3 + 1] - qy;
    float rz = spos[s * 3 + 2] - qz;
    cnt += 1.f;
    sx += rx; sy += ry; sz += rz;
    sxx += rx * rx; syy += ry * ry; szz += rz * rz;
    mnx = fminf(mnx, rx); mny = fminf(mny, ry); mnz = fminf(mnz, rz);
    mxx = fmaxf(mxx, rx); mxy = fmaxf(mxy, ry); mxz = fmaxf(mxz, rz);
  }
#pragma unroll
  for (int msk = 1; msk <= 2; msk <<= 1) {
    cnt += __shfl_xor(cnt, msk);
    sx += __shfl_xor(sx, msk); sy += __shfl_xor(sy, msk); sz += __shfl_xor(sz, msk);
    sxx += __shfl_xor(sxx, msk); syy += __shfl_xor(syy, msk); szz += __shfl_xor(szz, msk);
    mnx = fminf(mnx, __shfl_xor(mnx, msk));
    mny = fminf(mny, __shfl_xor(mny, msk));
    mnz = fminf(mnz, __shfl_xor(mnz, msk));
    mxx = fmaxf(mxx, __shfl_xor(mxx, msk));
    mxy = fmaxf(mxy, __shfl_xor(mxy, msk));
    mxz = fmaxf(mxz, __shfl_xor(mxz, msk));
  }
  if (sub == 0) {
    float c = fmaxf(cnt, 1.f);
    float mx_ = sx / c, my_ = sy / c, mz_ = sz / c;
    float vx = fmaxf(sxx / c - mx_ * mx_, 0.f);
    float vy = fmaxf(syy / c - my_ * my_, 0.f);
    float vz = fmaxf(szz / c - mz_ * mz_, 0.f);
    float* r = raw + (size_t)q * 12;
    r[0] = mx_; r[1] = my_; r[2] = mz_;
    r[3] = sqrtf(vx); r[4] = sqrtf(vy); r[5] = sqrtf(vz);
    r[6] = fminf(fmaxf(mnx, -100.f), 100.f);
    r[7] = fminf(fmaxf(mny, -100.f), 100.f);
    r[8] = fminf(fmaxf(mnz, -100.f), 100.f);
    r[9] = fminf(fmaxf(mxx, -100.f), 100.f);
    r[10] = fminf(fmaxf(mxy, -100.f), 100.f);
    r[11] = fminf(fmaxf(mxz, -100.f), 100.f);
  }
}

// ---------------- geo MLP: raw [Q,12] -> geo bf16 [Q,128], 8 queries/block ----------------
__global__ __launch_bounds__(128) void geo_mlp_kernel(
    const float* raw, const float* Gw1, const float* Gb1,
    const float* Gw2, const float* Gb2, unsigned short* geo_b) {
  int qb = blockIdx.x * 8;
  int j = threadIdx.x;
  __shared__ float rs[8][12];
  __shared__ float h1[8][128];
  if (j < 96) rs[j / 12][j % 12] = raw[(size_t)(qb + j / 12) * 12 + (j % 12)];
  __syncthreads();
  float b1 = Gb1[j];
  float acc[8];
#pragma unroll
  for (int qq = 0; qq < 8; ++qq) acc[qq] = b1;
  for (int i = 0; i < 12; ++i) {
    float w = Gw1[i * GEON + j];
#pragma unroll
    for (int qq = 0; qq < 8; ++qq) acc[qq] += rs[qq][i] * w;
  }
#pragma unroll
  for (int qq = 0; qq < 8; ++qq) h1[qq][j] = gelu_f(acc[qq]);
  __syncthreads();
  float b2 = Gb2[j];
  float acc2[8];
#pragma unroll
  for (int qq = 0; qq < 8; ++qq) acc2[qq] = b2;
  for (int k = 0; k < 128; ++k) {
    float w = Gw2[k * GEON + j];
#pragma unroll
    for (int qq = 0; qq < 8; ++qq) acc2[qq] += h1[qq][k] * w;
  }
#pragma unroll
  for (int qq = 0; qq < 8; ++qq)
    geo_b[(size_t)(qb + qq) * GEON + j] = f2b(gelu_f(acc2[qq]));
}

// ---------------- layernorm fp32 [Q,256] -> bf16, one wave per row ----------------
__global__ __launch_bounds__(256) void ln_kernel(
    const float* x, const float* g, const float* b, unsigned short* out) {
  int row = blockIdx.x * 4 + (threadIdx.x >> 6);
  int lane = threadIdx.x & 63;
  const float* xr = x + (size_t)row * DN;
  float4 v = *(const float4*)(xr + lane * 4);
  float s = v.x + v.y + v.z + v.w;
  float ss = v.x * v.x + v.y * v.y + v.z * v.z + v.w * v.w;
#pragma unroll
  for (int msk = 1; msk <= 32; msk <<= 1) {
    s += __shfl_xor(s, msk);
    ss += __shfl_xor(ss, msk);
  }
  float mean = s * (1.f / 256.f);
  float var = ss * (1.f / 256.f) - mean * mean;
  float rs = 1.0f / sqrtf(var + 1e-5f);
  float4 gg = *(const float4*)(g + lane * 4);
  float4 bb = *(const float4*)(b + lane * 4);
  unsigned short* o = out + (size_t)row * DN + lane * 4;
  o[0] = f2b((v.x - mean) * rs * gg.x + bb.x);
  o[1] = f2b((v.y - mean) * rs * gg.y + bb.y);
  o[2] = f2b((v.z - mean) * rs * gg.z + bb.z);
  o[3] = f2b((v.w - mean) * rs * gg.w + bb.w);
}

// ---------------- specialized KV GEMM ----------------
// KV[32768,512] = bf16( fp32 A[32768,256] @ B ), BT bf16 [512,256].
// One block = 64 rows x 512 cols. A staged ONCE (fp32->bf16, 32KB); B in 16
// col-tiles of 32 (16KB) -> 48KB LDS total. XOR swizzle in 8-el groups:
// phys_g = g ^ (row&7) -> staging writes and fragment reads are both at the
// 8-access/bank minimum (conflict-free for b128).
__device__ __forceinline__ u16x8* lds_g(unsigned short* base, int row, int col) {
  int g = (col >> 3) ^ (row & 7);
  return reinterpret_cast<u16x8*>(base + row * 256 + g * 8);
}
__global__ __launch_bounds__(256) void kv_gemm(
    const float* A, const unsigned short* BT, unsigned short* KVb) {
  __shared__ unsigned short As[64 * 256];   // 32 KB
  __shared__ unsigned short Bs[32 * 256];   // 16 KB
  int t = threadIdx.x;
  int bm = blockIdx.x * 64;
  int w = t >> 6, lane = t & 63;
  int quad = lane >> 4, l16 = lane & 15;
  int wr = w >> 1, wc = w & 1;   // wr: 32-row half; wc: 16-col half of the 32-col tile
  int srow = t >> 2, sub = t & 3;
  // stage A tile once: 64 rows x 256 K, fp32 -> bf16
  {
    const float* Ag = A + (size_t)(bm + srow) * 256 + sub * 64;
#pragma unroll
    for (int i = 0; i < 8; ++i) {
      float4 f0 = *(const float4*)(Ag + i * 8);
      float4 f1 = *(const float4*)(Ag + i * 8 + 4);
      u16x8 u;
      u[0] = f2b(f0.x); u[1] = f2b(f0.y); u[2] = f2b(f0.z); u[3] = f2b(f0.w);
      u[4] = f2b(f1.x); u[5] = f2b(f1.y); u[6] = f2b(f1.z); u[7] = f2b(f1.w);
      *lds_g(As, srow, sub * 64 + i * 8) = u;
    }
  }
  int brow = t >> 3, bsub = t & 7;  // 32 rows x 8 chunks of 32 for B staging
  for (int ct = 0; ct < 16; ++ct) {
    {
      const unsigned short* Bg = BT + (size_t)(ct * 32 + brow) * 256 + bsub * 32;
#pragma unroll
      for (int i = 0; i < 4; ++i)
        *lds_g(Bs, brow, bsub * 32 + i * 8) = *reinterpret_cast<const u16x8*>(Bg + i * 8);
    }
    __syncthreads();
    f32x4 acc[2];
    acc[0] = (f32x4){0.f, 0.f, 0.f, 0.f};
    acc[1] = (f32x4){0.f, 0.f, 0.f, 0.f};
#pragma unroll
    for (int k = 0; k < 8; ++k) {
      bf16x8 a0 = *reinterpret_cast<bf16x8*>(lds_g(As, wr * 32 + l16, k * 32 + quad * 8));
      bf16x8 a1 = *reinterpret_cast<bf16x8*>(lds_g(As, wr * 32 + 16 + l16, k * 32 + quad * 8));
      bf16x8 b0 = *reinterpret_cast<bf16x8*>(lds_g(Bs, wc * 16 + l16, k * 32 + quad * 8));
      acc[0] = __builtin_amdgcn_mfma_f32_16x16x32_bf16(a0, b0, acc[0], 0, 0, 0);
      acc[1] = __builtin_amdgcn_mfma_f32_16x16x32_bf16(a1, b0, acc[1], 0, 0, 0);
    }
#pragma unroll
    for (int i = 0; i < 2; ++i)
#pragma unroll
      for (int r = 0; r < 4; ++r) {
        int rw = bm + wr * 32 + i * 16 + quad * 4 + r;
        int col = ct * 32 + wc * 16 + l16;
        KVb[(size_t)rw * 512 + col] = f2b(acc[i][r]);
      }
    __syncthreads();  // protect Bs before next restage
  }
}

// ---------------- generic bf16 MFMA GEMM, 64x64 tile (R5 proven) ----------------
template <bool A_FP32, bool COLGRID, bool HAS_BIAS, bool DO_GELU, bool HAS_RESID, bool STORE_F32>
__global__ __launch_bounds__(256) void gemm64(
    const void* Ap, const unsigned short* BT, int M, int N, int K,
    const float* bias, const float* resid, float* outF, unsigned short* outB) {
  __shared__ unsigned short As[64][40];
  __shared__ unsigned short Bs[64][40];
  int t = threadIdx.x;
  int bm = (COLGRID ? blockIdx.x : blockIdx.y) * 64;
  int bn = (COLGRID ? blockIdx.y : blockIdx.x) * 64;
  int w = t >> 6, lane = t & 63;
  int wr = w >> 1, wc = w & 1;
  int quad = lane >> 4, l16 = lane & 15;
  int row = t >> 2, chunk = t & 3;

  f32x4 acc[2][2];
#pragma unroll
  for (int i = 0; i < 2; ++i)
#pragma unroll
    for (int j = 0; j < 2; ++j) acc[i][j] = (f32x4){0.f, 0.f, 0.f, 0.f};

  for (int k0 = 0; k0 < K; k0 += 32) {
    if (A_FP32) {
      const float* Ag = (const float*)Ap + (size_t)(bm + row) * K + k0 + chunk * 8;
      float4 f0 = *(const float4*)Ag;
      float4 f1 = *(const float4*)(Ag + 4);
      u16x8 u;
      u[0] = f2b(f0.x); u[1] = f2b(f0.y); u[2] = f2b(f0.z); u[3] = f2b(f0.w);
      u[4] = f2b(f1.x); u[5] = f2b(f1.y); u[6] = f2b(f1.z); u[7] = f2b(f1.w);
      *reinterpret_cast<u16x8*>(&As[row][chunk * 8]) = u;
    } else {
      const unsigned short* Ag = (const unsigned short*)Ap + (size_t)(bm + row) * K + k0 + chunk * 8;
      *reinterpret_cast<u16x8*>(&As[row][chunk * 8]) = *reinterpret_cast<const u16x8*>(Ag);
    }
    {
      const unsigned short* Bg = BT + (size_t)(bn + row) * K + k0 + chunk * 8;
      *reinterpret_cast<u16x8*>(&Bs[row][chunk * 8]) = *reinterpret_cast<const u16x8*>(Bg);
    }
    __syncthreads();
    bf16x8 a0 = *reinterpret_cast<const bf16x8*>(&As[wr * 32 + l16][quad * 8]);
    bf16x8 a1 = *reinterpret_cast<const bf16x8*>(&As[wr * 32 + 16 + l16][quad * 8]);
    bf16x8 b0 = *reinterpret_cast<const bf16x8*>(&Bs[wc * 32 + l16][quad * 8]);
    bf16x8 b1 = *reinterpret_cast<const bf16x8*>(&Bs[wc * 32 + 16 + l16][quad * 8]);
    acc[0][0] = __builtin_amdgcn_mfma_f32_16x16x32_bf16(a0, b0, acc[0][0], 0, 0, 0);
    acc[0][1] = __builtin_amdgcn_mfma_f32_16x16x32_bf16(a0, b1, acc[0][1], 0, 0, 0);
    acc[1][0] = __builtin_amdgcn_mfma_f32_16x16x32_bf16(a1, b0, acc[1][0], 0, 0, 0);
    acc[1][1] = __builtin_amdgcn_mfma_f32_16x16x32_bf16(a1, b1, acc[1][1], 0, 0, 0);
    __syncthreads();
  }

#pragma unroll
  for (int i = 0; i < 2; ++i)
#pragma unroll
    for (int j = 0; j < 2; ++j) {
      int col = bn + wc * 32 + j * 16 + l16;
      float bv = HAS_BIAS ? bias[col] : 0.f;
#pragma unroll
      for (int r = 0; r < 4; ++r) {
        int rw = bm + wr * 32 + i * 16 + quad * 4 + r;
        float v = acc[i][j][r] + bv;
        if (DO_GELU) v = gelu_f(v);
        if (HAS_RESID) v += resid[(size_t)rw * N + col];
        if (STORE_F32) outF[(size_t)rw * N + col] = v;
        else outB[(size_t)rw * N + col] = f2b(v);
      }
    }
}

// ---------------- edge attention: one wave/query, 2 edges per iteration ----------------
// Lane map: 32 lanes per edge-slot (half = lane>>5 picks edge e or e+1);
// within slot: head = (lane&31)>>2, 8 elements per lane (16B loads).
// Two online-softmax states merged at the end (guarded exp -> NaN-free for
// empty segments and odd edge counts).
__global__ __launch_bounds__(256) void attn_edge_kernel(
    const unsigned short* Qb, const unsigned short* Gfb, const unsigned short* KVb,
    const int* s_idx, const int* offs, const float* log_tau, unsigned short* attn_b) {
  int q = blockIdx.x * 4 + (threadIdx.x >> 6);
  int lane = threadIdx.x & 63;
  int half = lane >> 5;
  int sl = lane & 31;
  int d0 = sl * 8;
  int e0 = offs[q], e1 = offs[q + 1];
  float invs = expf(-log_tau[0]) * 0.17677669529663687f;  // 1/(sqrt(32)*tau)
  u16x8 qu = *(const u16x8*)(Qb + (size_t)q * DN + d0);
  u16x8 gu = *(const u16x8*)(Gfb + (size_t)q * DN + d0);
  float qf[8], gf[8];
#pragma unroll
  for (int j = 0; j < 8; ++j) { qf[j] = b2f(qu[j]) * invs; gf[j] = b2f(gu[j]); }
  const float NEG = -1e30f;
  float m = -INFINITY, l = 0.f;
  float a[8];
#pragma unroll
  for (int j = 0; j < 8; ++j) a[j] = 0.f;
  for (int e = e0; e < e1; e += 2) {
    int ee = e + half;
    bool valid = ee < e1;
    int s = s_idx[valid ? ee : (e1 - 1)];
    const unsigned short* kr = KVb + (size_t)s * 512 + d0;
    u16x8 ku = *(const u16x8*)kr;
    u16x8 vu = *(const u16x8*)(kr + 256);
    float p = 0.f;
#pragma unroll
    for (int j = 0; j < 8; ++j) p += qf[j] * b2f(ku[j]);
    p += __shfl_xor(p, 1);
    p += __shfl_xor(p, 2);       // per-head score across the head's 4 lanes
    if (!valid) p = -INFINITY;
    float mnew = fmaxf(m, p);
    float sc = (m > NEG) ? __expf(m - mnew) : 0.f;
    float we = valid ? __expf(p - mnew) : 0.f;
    l = l * sc + we;
#pragma unroll
    for (int j = 0; j < 8; ++j) a[j] = a[j] * sc + we * (b2f(vu[j]) + gf[j]);
    m = mnew;
  }
  // merge the two half-wave states
  float om = __shfl_xor(m, 32);
  float ol = __shfl_xor(l, 32);
  float M2 = fmaxf(m, om);
  float ws = (m > NEG) ? __expf(m - M2) : 0.f;
  float wo = (om > NEG) ? __expf(om - M2) : 0.f;
  l = l * ws + ol * wo;
#pragma unroll
  for (int j = 0; j < 8; ++j) {
    float oa = __shfl_xor(a[j], 32);
    a[j] = a[j] * ws + oa * wo;
  }
  // reference: M = max(0, seg_max); denom = max(sum exp(s-M), 1e-8)
  float M = fmaxf(M2, 0.f);
  float em = (M2 > NEG) ? __expf(M2 - M) : 0.f;
  float denom = fmaxf(l * em, 1e-8f);
  float f = em / denom;
  if (half == 0) {
    u16x8 o;
#pragma unroll
    for (int j = 0; j < 8; ++j) o[j] = f2b(a[j] * f);
    *(u16x8*)(attn_b + (size_t)q * DN + d0) = o;
  }
}

extern "C" void kernel_launch(void* const* d_in, const int* in_sizes, int n_in,
                              void* d_out, int out_size, void* d_ws, size_t ws_size,
                              hipStream_t stream) {
  const float* query_tokens  = (const float*)d_in[0];
  const float* query_pos     = (const float*)d_in[1];
  const float* support_feats = (const float*)d_in[2];
  const float* support_pos   = (const float*)d_in[3];
  const float* Wq  = (const float*)d_in[4];
  const float* Wk  = (const float*)d_in[5];
  const float* Wv  = (const float*)d_in[6];
  const float* Wg  = (const float*)d_in[7];
  const float* Wo  = (const float*)d_in[8];
  const float* bo  = (const float*)d_in[9];
  const float* log_tau = (const float*)d_in[10];
  const float* ln1_g = (const float*)d_in[11];
  const float* ln1_b = (const float*)d_in[12];
  const float* ln2_g = (const float*)d_in[13];
  const float* ln2_b = (const float*)d_in[14];
  const float* Wf1 = (const float*)d_in[15];
  const float* bf1 = (const float*)d_in[16];
  const float* Wf2 = (const float*)d_in[17];
  const float* bf2 = (const float*)d_in[18];
  const float* Gw1 = (const float*)d_in[19];
  const float* Gb1 = (const float*)d_in[20];
  const float* Gw2 = (const float*)d_in[21];
  const float* Gb2 = (const float*)d_in[22];
  const int* q_idx = (const int*)d_in[23];
  const int* s_idx = (const int*)d_in[24];
  float* out = (float*)d_out;

  char* ws = (char*)d_ws;
  size_t off = 0;
  auto alloc = [&](size_t bytes) -> void* {
    void* p = ws + off;
    off = (off + bytes + 255) & ~(size_t)255;
    return p;
  };
  unsigned short* WqT  = (unsigned short*)alloc(65536 * 2);
  unsigned short* WkvT = (unsigned short*)alloc(131072 * 2);
  unsigned short* WgT  = (unsigned short*)alloc(32768 * 2);
  unsigned short* WoT  = (unsigned short*)alloc(65536 * 2);
  unsigned short* Wf1T = (unsigned short*)alloc(131072 * 2);
  unsigned short* Wf2T = (unsigned short*)alloc(131072 * 2);
  int* offs            = (int*)alloc((QN + 1) * 4);
  float* raw           = (float*)alloc((size_t)QN * 12 * 4);
  unsigned short* geo_b = (unsigned short*)alloc((size_t)QN * GEON * 2);
  unsigned short* qt_b  = (unsigned short*)alloc((size_t)QN * DN * 2);
  unsigned short* Qb    = (unsigned short*)alloc((size_t)QN * DN * 2);
  unsigned short* Gf_b  = (unsigned short*)alloc((size_t)QN * DN * 2);
  unsigned short* KVb   = (unsigned short*)alloc((size_t)SN * 512 * 2);
  unsigned short* attn_b = (unsigned short*)alloc((size_t)QN * DN * 2);
  float* x1             = (float*)alloc((size_t)QN * DN * 4);
  unsigned short* z_b   = (unsigned short*)alloc((size_t)QN * DN * 2);
  unsigned short* h_b   = (unsigned short*)alloc((size_t)QN * FFNN * 2);

  // 1. weight prep (bf16 transposed copies), tiled/coalesced
  transpose_weights<<<136, 256, 0, stream>>>(Wq, Wk, Wv, Wg, Wo, Wf1, Wf2,
                                             WqT, WkvT, WgT, WoT, Wf1T, Wf2T);
  // 2. segment offsets
  seg_offsets<<<33, 256, 0, stream>>>(q_idx, offs);
  // 3. geo stats
  geo_stats_kernel<<<QN / 64, 256, 0, stream>>>(query_pos, support_pos, offs, s_idx, raw);
  // 4. geo MLP
  geo_mlp_kernel<<<QN / 8, 128, 0, stream>>>(raw, Gw1, Gb1, Gw2, Gb2, geo_b);
  // 5. LN1
  ln_kernel<<<QN / 4, 256, 0, stream>>>(query_tokens, ln1_g, ln1_b, qt_b);
  // 6. KV = support_feats @ [Wk|Wv] — specialized, A staged once
  kv_gemm<<<SN / 64, 256, 0, stream>>>(support_feats, WkvT, KVb);
  // 7. Qf = qt @ Wq, store bf16
  gemm64<false, true, false, false, false, false><<<dim3(QN / 64, DN / 64), 256, 0, stream>>>(
      qt_b, WqT, QN, DN, 256, nullptr, nullptr, nullptr, Qb);
  // 8. Gf = geo @ Wg, store bf16
  gemm64<false, true, false, false, false, false><<<dim3(QN / 64, DN / 64), 256, 0, stream>>>(
      geo_b, WgT, QN, DN, 128, nullptr, nullptr, nullptr, Gf_b);
  // 9. edge attention -> attn_b bf16
  attn_edge_kernel<<<QN / 4, 256, 0, stream>>>(Qb, Gf_b, KVb, s_idx, offs, log_tau, attn_b);
  // 10. x1 = attn @ Wo + bo + query_tokens, store fp32
  gemm64<false, true, true, false, true, true><<<dim3(QN / 64, DN / 64), 256, 0, stream>>>(
      attn_b, WoT, QN, DN, 256, bo, query_tokens, x1, nullptr);
  // 11. LN2
  ln_kernel<<<QN / 4, 256, 0, stream>>>(x1, ln2_g, ln2_b, z_b);
  // 12. h = gelu(z @ Wf1 + bf1), store bf16
  gemm64<false, true, true, true, false, false><<<dim3(QN / 64, FFNN / 64), 256, 0, stream>>>(
      z_b, Wf1T, QN, FFNN, 256, bf1, nullptr, nullptr, h_b);
  // 13. out = h @ Wf2 + bf2 + x1, store fp32 -> d_out
  gemm64<false, true, true, false, true, true><<<dim3(QN / 64, DN / 64), 256, 0, stream>>>(
      h_b, Wf2T, QN, DN, 512, bf2, x1, out, nullptr);

  (void)in_sizes; (void)n_in; (void)out_size; (void)ws_size;
}